// Round 5
// baseline (3639.067 us; speedup 1.0000x reference)
//
#include <hip/hip_runtime.h>

// LSTM: SEQ=256, INPUT_DIM=1, HIDDEN=1024, NUM_CLASSES=10, BATCH=512, fp32 in/out.
// Persistent kernel, 256 wgs x 256 threads, 1 wg/CU. wg (r,c): h-slice [32r,32r+32),
// batch-slice [64c,64c+64). Wave w owns h-sub [32r+8w,+8); one 32x32x16 MFMA tile packs
// all 4 gates (rows = gate*8+dh) -> gates co-located per lane.
// ht exchange: agent-scope ATOMIC EXCHANGE stores (complete at L3 coherence point — no
// HBM write-through on the critical path) + per-WAVE flag words + all-wave parallel poll
// (no __syncthreads in the step loop at all; chunk s_barriers + the poll itself provide
// all needed ordering: poll target includes own wg's waves => no LDS WAR across steps).

#define HID  1024
#define SEQL 256

typedef __bf16 bf16x8 __attribute__((ext_vector_type(8)));
typedef float  f32x16 __attribute__((ext_vector_type(16)));
typedef unsigned u32x4 __attribute__((ext_vector_type(4)));

#define AS1 __attribute__((address_space(1)))
#define AS3 __attribute__((address_space(3)))

__device__ __forceinline__ float fast_sigmoid(float v) {
    float e = __expf(-v);
    return 1.0f / (1.0f + e);
}
__device__ __forceinline__ float fast_tanh(float v) {
    float e = __expf(2.0f * v);          // saturates correctly at +/-inf
    return 1.0f - 2.0f / (e + 1.0f);
}
__device__ __forceinline__ unsigned pk2bf(float a, float b) {
    unsigned short ua = __builtin_bit_cast(unsigned short, (__bf16)a);
    unsigned short ub = __builtin_bit_cast(unsigned short, (__bf16)b);
    return (unsigned)ua | ((unsigned)ub << 16);
}
__device__ __forceinline__ float bfhi(unsigned u) { return __builtin_bit_cast(float, u & 0xFFFF0000u); }
__device__ __forceinline__ float bflo(unsigned u) { return __builtin_bit_cast(float, u << 16); }

// device-scope (sc1) 16B load — coherent across XCDs, bypasses stale L1/L2
__device__ __forceinline__ u32x4 load16_sc1(const void* p) {
    u32x4 r;
    asm volatile("global_load_dwordx4 %0, %1, off sc1\n\t"
                 "s_waitcnt vmcnt(0)"
                 : "=v"(r) : "v"(p) : "memory");
    return r;
}

__global__ __launch_bounds__(256) void lstm_init(unsigned short* htA, unsigned* flags, float* out) {
    int idx = blockIdx.x * 256 + threadIdx.x;          // 65536 threads
    uint4 z; z.x = 0; z.y = 0; z.z = 0; z.w = 0;
    ((uint4*)htA)[idx] = z;                            // zero 1 MB (ht(-1) = 0, frag order)
    if (idx < 1024) flags[idx] = 0;                    // 8 groups x 128 per-wave flags
    if (idx < 5120) out[idx] = 0.05f;                  // sentinel, overwritten by lstm_main
}

__global__ __attribute__((amdgpu_flat_work_group_size(256, 256), amdgpu_waves_per_eu(1, 1)))
void lstm_main(
    const float* __restrict__ x,
    const float* __restrict__ Wgx, const float* __restrict__ Wgh, const float* __restrict__ bg,
    const float* __restrict__ Wix, const float* __restrict__ Wih, const float* __restrict__ bi,
    const float* __restrict__ Wfx, const float* __restrict__ Wfh, const float* __restrict__ bf_,
    const float* __restrict__ Wox, const float* __restrict__ Woh, const float* __restrict__ bo,
    const float* __restrict__ Wph, const float* __restrict__ bp,
    float* __restrict__ out,
    unsigned short* __restrict__ htA, unsigned short* __restrict__ htB,
    unsigned* __restrict__ flags)
{
    // B-fragment staging: [chunk4][kk_local(16)][nt(2)][lane(64)] of 16B -> 128 KiB dynamic
    extern __shared__ uint4 ldsB[];

    const int tid = threadIdx.x;
    const int w   = tid >> 6;        // wave 0..3
    const int l   = tid & 63;
    const int l31 = l & 31;
    const int h5  = l >> 5;
    const int gid = blockIdx.x;
    const int c   = gid & 7;         // batch group (64 batches)
    const int r   = gid >> 3;        // h group (32 h)

    // ---- load A fragments (weights, bf16) into registers: 64 k-steps x bf16x8 ----
    // A row m = l31: gate = m>>3, dh = m&7 ; within one MFMA, k = h5*8 + e
    const int gate = l31 >> 3;
    const int hrow = (r << 5) + (w << 3) + (l & 7);
    const float* Wsel = (gate == 0) ? Wgh : (gate == 1) ? Wih : (gate == 2) ? Wfh : Woh;
    const float* wrow = Wsel + hrow * HID + (h5 << 3);
    bf16x8 A[64];
#pragma unroll
    for (int kk = 0; kk < 64; ++kk) {
        const float4* p = (const float4*)(wrow + kk * 16);
        float4 u0 = p[0], u1 = p[1];
        bf16x8 a;
        a[0] = (__bf16)u0.x; a[1] = (__bf16)u0.y; a[2] = (__bf16)u0.z; a[3] = (__bf16)u0.w;
        a[4] = (__bf16)u1.x; a[5] = (__bf16)u1.y; a[6] = (__bf16)u1.z; a[7] = (__bf16)u1.w;
        A[kk] = a;
        __builtin_amdgcn_sched_barrier(0);   // bound register pressure during init
    }

    // ---- per-lane Wx / bias for the 16 accumulator rows ----
    // acc reg j -> D row = (j&3) + 8*(j>>2) + 4*h5  => gate=j>>2, dh=(j&3)+4*h5
    float wx16[16], bs16[16];
    {
        const float* WxA[4] = {Wgx, Wix, Wfx, Wox};
        const float* bA[4]  = {bg, bi, bf_, bo};
#pragma unroll
        for (int j = 0; j < 16; ++j) {
            int g = j >> 2;
            int h = (r << 5) + (w << 3) + (j & 3) + (h5 << 2);
            wx16[j] = WxA[g][h];
            bs16[j] = bA[g][h];
        }
    }

    float ct[8];
#pragma unroll
    for (int i = 0; i < 8; ++i) ct[i] = 0.f;

    const unsigned short* htR = htA;   // ht(t-1), fragment order
    unsigned short*       htW = htB;   // ht(t)
    unsigned* gflags = flags + (c << 7);                      // 128 per-wave flags
    unsigned* myflag = gflags + (r << 2) + w;                 // this wave's flag
    const unsigned long long* pollp = (const unsigned long long*)gflags + l;  // flags[2l..2l+1]
    const float* xrow0 = x + (unsigned)((c << 6) + l31) * SEQL;
    const float* xrow1 = x + (unsigned)((c << 6) + 32 + l31) * SEQL;

    float xv0 = xrow0[0], xv1 = xrow1[0];   // x for t=0

    for (int t = 0; t < SEQL; ++t) {
        // ---- poll: all 128 wave-flags of this group must have reached t ----
        // (also orders intra-wg LDS reuse: own wg's waves flagged => done reading ldsB)
        unsigned target = (unsigned)t;
        if (t > 0) {
            while (true) {
                unsigned long long v = __hip_atomic_load(pollp, __ATOMIC_RELAXED,
                                                         __HIP_MEMORY_SCOPE_AGENT);
                bool ok = ((unsigned)v >= target) && ((unsigned)(v >> 32) >= target);
                if (__ballot(ok) == ~0ull) break;
                __builtin_amdgcn_s_sleep(1);
            }
        }

        const unsigned short* gR = htR + (c << 16);   // this group's 128 KiB region

        // ---- issue ALL 4 chunks (each wave: 32 x global_load_lds of 1 KiB, sc1) ----
#pragma unroll
        for (int ch = 0; ch < 4; ++ch) {
#pragma unroll
            for (int j = 0; j < 8; ++j) {
                int q = (w << 3) + j;                  // pair id = kk_local*2 + nt
                const void* g = (const void*)(gR + ch * 16384 + q * 512 + (l << 3));
                __builtin_amdgcn_global_load_lds((const AS1 void*)g,
                    (AS3 void*)&ldsB[(ch * 32 + q) * 64], 16, 0, 0x10 /*sc1*/);
            }
        }
        __builtin_amdgcn_sched_barrier(0);
        // prefetch x for t+1 (stays outstanding through the chunk drains; used next iter)
        int tn = (t + 1 < SEQL) ? t + 1 : t;
        float nx0 = xrow0[tn], nx1 = xrow1[tn];
        __builtin_amdgcn_sched_barrier(0);

        // init accumulators with bias + Wx*x_t (xv already in regs: pure VALU)
        f32x16 acc0, acc1;
#pragma unroll
        for (int j = 0; j < 16; ++j) {
            acc0[j] = fmaf(wx16[j], xv0, bs16[j]);
            acc1[j] = fmaf(wx16[j], xv1, bs16[j]);
        }

        // ---- K loop: 4 chunks, counted drains (later chunks + x stay in flight) ----
#pragma unroll
        for (int ch = 0; ch < 4; ++ch) {
            if      (ch == 0) asm volatile("s_waitcnt vmcnt(26)" ::: "memory");
            else if (ch == 1) asm volatile("s_waitcnt vmcnt(18)" ::: "memory");
            else if (ch == 2) asm volatile("s_waitcnt vmcnt(10)" ::: "memory");
            else              asm volatile("s_waitcnt vmcnt(2)"  ::: "memory");
            __builtin_amdgcn_s_barrier();
            asm volatile("" ::: "memory");
#pragma unroll
            for (int kk = 0; kk < 16; ++kk) {
                bf16x8 b0 = __builtin_bit_cast(bf16x8, ldsB[(ch * 32 + kk * 2 + 0) * 64 + l]);
                bf16x8 b1 = __builtin_bit_cast(bf16x8, ldsB[(ch * 32 + kk * 2 + 1) * 64 + l]);
                acc0 = __builtin_amdgcn_mfma_f32_32x32x16_bf16(A[ch * 16 + kk], b0, acc0, 0, 0, 0);
                acc1 = __builtin_amdgcn_mfma_f32_32x32x16_bf16(A[ch * 16 + kk], b1, acc1, 0, 0, 0);
            }
        }

        // ---- activations + state update (all 4 gates live in this lane) ----
        float htv[8];
#pragma unroll
        for (int nt = 0; nt < 2; ++nt) {
            f32x16 ac = nt ? acc1 : acc0;
#pragma unroll
            for (int d = 0; d < 4; ++d) {
                float g  = fast_tanh(ac[d]);
                float ii = fast_sigmoid(ac[4 + d]);
                float ff = fast_sigmoid(ac[8 + d]);
                float oo = fast_sigmoid(ac[12 + d]);
                float cc = fmaf(ct[nt * 4 + d], ff, g * ii);
                ct[nt * 4 + d] = cc;
                htv[nt * 4 + d] = fast_tanh(cc) * oo;
            }
        }

        // ---- publish ht(t): agent-scope atomic exchange (completes at L3, no HBM WT) ----
        {
            unsigned short* gW = htW + (c << 16);
            int kkw  = (r << 1) + (w >> 1);
            int slot = ((w & 1) << 5) + l31;
#pragma unroll
            for (int nt = 0; nt < 2; ++nt) {
                unsigned lo = pk2bf(htv[nt * 4 + 0], htv[nt * 4 + 1]);
                unsigned hi = pk2bf(htv[nt * 4 + 2], htv[nt * 4 + 3]);
                unsigned long long v = (unsigned long long)lo | ((unsigned long long)hi << 32);
                unsigned long long* dst =
                    (unsigned long long*)(gW + (((kkw * 2 + nt) * 64 + slot) * 8 + (h5 << 2)));
                (void)__hip_atomic_exchange(dst, v, __ATOMIC_RELAXED, __HIP_MEMORY_SCOPE_AGENT);
            }
        }
        // wave's ht swaps done at coherence point, then raise this wave's flag
        asm volatile("s_waitcnt vmcnt(0)" ::: "memory");
        if (l == 0)
            (void)__hip_atomic_exchange(myflag, (unsigned)(t + 1),
                                        __ATOMIC_RELAXED, __HIP_MEMORY_SCOPE_AGENT);

        xv0 = nx0; xv1 = nx1;
        const unsigned short* tmp = htR; htR = htW; htW = (unsigned short*)tmp;
    }

    // ---- final poll: everyone's step-256 flag, then projection ----
    {
        unsigned target = (unsigned)SEQL;
        while (true) {
            unsigned long long v = __hip_atomic_load(pollp, __ATOMIC_RELAXED,
                                                     __HIP_MEMORY_SCOPE_AGENT);
            bool ok = ((unsigned)v >= target) && ((unsigned)(v >> 32) >= target);
            if (__ballot(ok) == ~0ull) break;
            __builtin_amdgcn_s_sleep(1);
        }
    }

    // ---- final projection: out[b][cls] = Wph[cls,:] . ht[:,b] + bp[cls] ----
    //   elem(h, b) at region c*65536 + (h>>4)*1024 + ((b>>5)&1)*512 + ((h>>3)&1)*256 + (b&31)*8 + (h&7)
    // Lane l covers h in [16l, 16l+16): two 16B loads at +0 and +256 elems.
    {
        const unsigned short* hfin = htR + (c << 16);
        for (int p = w; p < 20; p += 4) {
            int bloc = (r << 1) + (p / 10);            // in-group batch 0..63
            int bb   = (c << 6) + bloc;
            int cls  = p % 10;
            const unsigned short* base = hfin + l * 1024 + ((bloc >> 5) & 1) * 512
                                              + (bloc & 31) * 8;
            u32x4 u0 = load16_sc1(base);               // h = 16l + 0..7
            u32x4 u1 = load16_sc1(base + 256);         // h = 16l + 8..15
            const float* wp = Wph + (unsigned)cls * HID + (unsigned)l * 16;
            float s = 0.f;
#pragma unroll
            for (int e = 0; e < 4; ++e) {
                s = fmaf(wp[2 * e],         bflo(u0[e]), s);
                s = fmaf(wp[2 * e + 1],     bfhi(u0[e]), s);
                s = fmaf(wp[8 + 2 * e],     bflo(u1[e]), s);
                s = fmaf(wp[8 + 2 * e + 1], bfhi(u1[e]), s);
            }
#pragma unroll
            for (int off = 32; off > 0; off >>= 1) s += __shfl_xor(s, off, 64);
            if (l == 0) out[bb * 10 + cls] = s + bp[cls];
        }
    }
}

extern "C" void kernel_launch(void* const* d_in, const int* in_sizes, int n_in,
                              void* d_out, int out_size, void* d_ws, size_t ws_size,
                              hipStream_t stream) {
    const float* x   = (const float*)d_in[0];
    const float* Wgx = (const float*)d_in[1];
    const float* Wgh = (const float*)d_in[2];
    const float* bg  = (const float*)d_in[3];
    const float* Wix = (const float*)d_in[4];
    const float* Wih = (const float*)d_in[5];
    const float* bi  = (const float*)d_in[6];
    const float* Wfx = (const float*)d_in[7];
    const float* Wfh = (const float*)d_in[8];
    const float* bf_ = (const float*)d_in[9];
    const float* Wox = (const float*)d_in[10];
    const float* Woh = (const float*)d_in[11];
    const float* bo  = (const float*)d_in[12];
    const float* Wph = (const float*)d_in[13];
    const float* bp  = (const float*)d_in[14];
    float* out = (float*)d_out;

    char* ws = (char*)d_ws;
    unsigned short* htA = (unsigned short*)ws;                 // 1 MiB, ht buffer A (frag order)
    unsigned short* htB = (unsigned short*)(ws + (1 << 20));   // 1 MiB, ht buffer B
    unsigned*     flags = (unsigned*)(ws + (2 << 20));         // 4 KiB, per-wave step flags

    lstm_init<<<dim3(256), dim3(256), 0, stream>>>(htA, flags, out);

    static int lds_set = 0;
    if (!lds_set) {   // idempotent, deterministic; allows 128 KiB dynamic LDS
        hipFuncSetAttribute((const void*)lstm_main,
                            hipFuncAttributeMaxDynamicSharedMemorySize, 131072);
        lds_set = 1;
    }
    lstm_main<<<dim3(256), dim3(256), 131072, stream>>>(
        x, Wgx, Wgh, bg, Wix, Wih, bi, Wfx, Wfh, bf_,
        Wox, Woh, bo, Wph, bp, out, htA, htB, flags);
}

// Round 6
// 1763.540 us; speedup vs baseline: 2.0635x; 2.0635x over previous
//
#include <hip/hip_runtime.h>

// LSTM: SEQ=256, INPUT_DIM=1, HIDDEN=1024, NUM_CLASSES=10, BATCH=512, fp32 in/out.
// Persistent kernel, 256 wgs x 256 threads, 1 wg/CU (128 KiB LDS forces it).
// wg (r,c): h-slice [32r,32r+32), batch-slice [64c,64c+64). Wave w owns h-sub [32r+8w,+8);
// one 32x32x16 MFMA tile packs all 4 gates (rows = gate*8+dh) -> gates co-located per lane.
// Batch groups (c = gid&7) are fully independent => with round-robin dispatch all 32 wgs of
// a group share one XCD and ht exchange is INTRA-L2: plain stores + sc0 loads. Verified at
// runtime via HW_REG_XCC_ID; non-uniform groups fall back to device-scope (sc1) ops.
// Step flags are always sc1 (no L2 copies ever -> replay-safe with init re-zeroing).

#define HID  1024
#define SEQL 256

typedef __bf16 bf16x8 __attribute__((ext_vector_type(8)));
typedef float  f32x16 __attribute__((ext_vector_type(16)));
typedef unsigned u32x4 __attribute__((ext_vector_type(4)));

#define AS1 __attribute__((address_space(1)))
#define AS3 __attribute__((address_space(3)))

__device__ __forceinline__ float fast_sigmoid(float v) {
    float e = __expf(-v);
    return 1.0f / (1.0f + e);
}
__device__ __forceinline__ float fast_tanh(float v) {
    float e = __expf(2.0f * v);          // saturates correctly at +/-inf
    return 1.0f - 2.0f / (e + 1.0f);
}
__device__ __forceinline__ unsigned pk2bf(float a, float b) {
    unsigned short ua = __builtin_bit_cast(unsigned short, (__bf16)a);
    unsigned short ub = __builtin_bit_cast(unsigned short, (__bf16)b);
    return (unsigned)ua | ((unsigned)ub << 16);
}
__device__ __forceinline__ float bfhi(unsigned u) { return __builtin_bit_cast(float, u & 0xFFFF0000u); }
__device__ __forceinline__ float bflo(unsigned u) { return __builtin_bit_cast(float, u << 16); }

__device__ __forceinline__ void store_sc1(unsigned* p, unsigned v) {
    asm volatile("global_store_dword %0, %1, off sc1" :: "v"(p), "v"(v) : "memory");
}
// device-scope (sc1) 16B load — coherent across XCDs (bypasses L1+L2, no allocate)
__device__ __forceinline__ u32x4 load16_sc1(const void* p) {
    u32x4 r;
    asm volatile("global_load_dwordx4 %0, %1, off sc1\n\t"
                 "s_waitcnt vmcnt(0)" : "=v"(r) : "v"(p) : "memory");
    return r;
}
// XCD-scope (sc0) 16B load — bypasses L1, served by this XCD's L2
__device__ __forceinline__ u32x4 load16_sc0(const void* p) {
    u32x4 r;
    asm volatile("global_load_dwordx4 %0, %1, off sc0\n\t"
                 "s_waitcnt vmcnt(0)" : "=v"(r) : "v"(p) : "memory");
    return r;
}

// sync region: [0..511] step flags (8 groups x 64 stride), [512..767] xcd slots
__global__ __launch_bounds__(256) void lstm_init(unsigned* sync, float* out) {
    int idx = blockIdx.x * 256 + threadIdx.x;          // 5120 threads
    if (idx < 768) store_sc1(sync + idx, 0u);          // sc1: no L2 copies anywhere
    if (idx < 5120) out[idx] = 0.05f;                  // sentinel, overwritten by lstm_main
}

__global__ __attribute__((amdgpu_flat_work_group_size(256, 256), amdgpu_waves_per_eu(1, 1)))
void lstm_main(
    const float* __restrict__ x,
    const float* __restrict__ Wgx, const float* __restrict__ Wgh, const float* __restrict__ bg,
    const float* __restrict__ Wix, const float* __restrict__ Wih, const float* __restrict__ bi,
    const float* __restrict__ Wfx, const float* __restrict__ Wfh, const float* __restrict__ bf_,
    const float* __restrict__ Wox, const float* __restrict__ Woh, const float* __restrict__ bo,
    const float* __restrict__ Wph, const float* __restrict__ bp,
    float* __restrict__ out,
    unsigned short* __restrict__ htA, unsigned short* __restrict__ htB,
    unsigned* __restrict__ sync)
{
    // B-fragment staging: [chunk4][kk_local(16)][nt(2)][lane(64)] of 16B -> 128 KiB dynamic
    extern __shared__ uint4 ldsB[];

    const int tid = threadIdx.x;
    const int w   = tid >> 6;        // wave 0..3
    const int l   = tid & 63;
    const int l31 = l & 31;
    const int h5  = l >> 5;
    const int gid = blockIdx.x;
    const int c   = gid & 7;         // batch group (64 batches) — XCD-aligned by round-robin
    const int r   = gid >> 3;        // h group (32 h)

    // ---- load A fragments (weights, bf16) into registers: 64 k-steps x bf16x8 ----
    // A row m = l31: gate = m>>3, dh = m&7 ; within one MFMA, k = h5*8 + e
    const int gate = l31 >> 3;
    const int hrow = (r << 5) + (w << 3) + (l & 7);
    const float* Wsel = (gate == 0) ? Wgh : (gate == 1) ? Wih : (gate == 2) ? Wfh : Woh;
    const float* wrow = Wsel + hrow * HID + (h5 << 3);
    bf16x8 A[64];
#pragma unroll
    for (int kk = 0; kk < 64; ++kk) {
        const float4* p = (const float4*)(wrow + kk * 16);
        float4 u0 = p[0], u1 = p[1];
        bf16x8 a;
        a[0] = (__bf16)u0.x; a[1] = (__bf16)u0.y; a[2] = (__bf16)u0.z; a[3] = (__bf16)u0.w;
        a[4] = (__bf16)u1.x; a[5] = (__bf16)u1.y; a[6] = (__bf16)u1.z; a[7] = (__bf16)u1.w;
        A[kk] = a;
        __builtin_amdgcn_sched_barrier(0);   // bound register pressure during init
    }

    // ---- per-lane Wx / bias for the 16 accumulator rows ----
    // acc reg j -> D row = (j&3) + 8*(j>>2) + 4*h5  => gate=j>>2, dh=(j&3)+4*h5
    float wx16[16], bs16[16];
    {
        const float* WxA[4] = {Wgx, Wix, Wfx, Wox};
        const float* bA[4]  = {bg, bi, bf_, bo};
#pragma unroll
        for (int j = 0; j < 16; ++j) {
            int g = j >> 2;
            int h = (r << 5) + (w << 3) + (j & 3) + (h5 << 2);
            wx16[j] = WxA[g][h];
            bs16[j] = bA[g][h];
        }
    }

    // ---- XCD-uniformity handshake (replay-safe: init re-zeroes slots each launch) ----
    unsigned xcd;
    asm volatile("s_getreg_b32 %0, hwreg(HW_REG_XCC_ID)" : "=s"(xcd));
    unsigned* xslot = sync + 512;
    if (tid == 0) store_sc1(xslot + gid, xcd + 1u);    // values 1..8
    bool fast;
    {
        const unsigned* sp = xslot + c + (l31 << 3);   // my group's 32 slots
        unsigned sv;
        while (true) {
            sv = __hip_atomic_load(sp, __ATOMIC_RELAXED, __HIP_MEMORY_SCOPE_AGENT);
            if (__ballot(sv >= 1u && sv <= 8u) == ~0ull) break;
            __builtin_amdgcn_s_sleep(1);
        }
        fast = (__ballot(sv == xcd + 1u) == ~0ull);    // group entirely on my XCD?
    }

    float ct[8];
#pragma unroll
    for (int i = 0; i < 8; ++i) ct[i] = 0.f;

    const unsigned short* htR = htA;   // ht(t-1), fragment order
    unsigned short*       htW = htB;   // ht(t)
    unsigned* gflags = sync + (c << 6);
    const float* xrow0 = x + (unsigned)((c << 6) + l31) * SEQL;
    const float* xrow1 = x + (unsigned)((c << 6) + 32 + l31) * SEQL;

    float xv0 = xrow0[0], xv1 = xrow1[0];   // x for t=0

    for (int t = 0; t < SEQL; ++t) {
        // prefetch x for t+1
        int tn = (t + 1 < SEQL) ? t + 1 : t;
        float nx0 = xrow0[tn], nx1 = xrow1[tn];

        // init accumulators with bias + Wx*x_t
        f32x16 acc0, acc1;
#pragma unroll
        for (int j = 0; j < 16; ++j) {
            acc0[j] = fmaf(wx16[j], xv0, bs16[j]);
            acc1[j] = fmaf(wx16[j], xv1, bs16[j]);
        }

        if (t > 0) {   // t==0: h(t-1)=0, no staging/MFMA at all
            const unsigned short* gR = htR + (c << 16);   // this group's 128 KiB region

            // ---- issue ALL 4 chunks (each wave: 32 x global_load_lds of 1 KiB) ----
            if (fast) {
#pragma unroll
                for (int ch = 0; ch < 4; ++ch)
#pragma unroll
                    for (int j = 0; j < 8; ++j) {
                        int q = (w << 3) + j;              // pair id = kk_local*2 + nt
                        const void* g = (const void*)(gR + ch * 16384 + q * 512 + (l << 3));
                        __builtin_amdgcn_global_load_lds((const AS1 void*)g,
                            (AS3 void*)&ldsB[(ch * 32 + q) * 64], 16, 0, 0x1 /*sc0: L2*/);
                    }
            } else {
#pragma unroll
                for (int ch = 0; ch < 4; ++ch)
#pragma unroll
                    for (int j = 0; j < 8; ++j) {
                        int q = (w << 3) + j;
                        const void* g = (const void*)(gR + ch * 16384 + q * 512 + (l << 3));
                        __builtin_amdgcn_global_load_lds((const AS1 void*)g,
                            (AS3 void*)&ldsB[(ch * 32 + q) * 64], 16, 0, 0x10 /*sc1*/);
                    }
            }
            __builtin_amdgcn_sched_barrier(0);

            // ---- K loop: 4 chunks, counted drains (later chunks stay in flight) ----
            // outstanding after staging: 32 stage loads (+2 x loads issued earlier,
            // already retired or counted conservatively)
#pragma unroll
            for (int ch = 0; ch < 4; ++ch) {
                if      (ch == 0) asm volatile("s_waitcnt vmcnt(24)" ::: "memory");
                else if (ch == 1) asm volatile("s_waitcnt vmcnt(16)" ::: "memory");
                else if (ch == 2) asm volatile("s_waitcnt vmcnt(8)"  ::: "memory");
                else              asm volatile("s_waitcnt vmcnt(0)"  ::: "memory");
                __builtin_amdgcn_s_barrier();
                asm volatile("" ::: "memory");
#pragma unroll
                for (int kk = 0; kk < 16; ++kk) {
                    bf16x8 b0 = __builtin_bit_cast(bf16x8, ldsB[(ch * 32 + kk * 2 + 0) * 64 + l]);
                    bf16x8 b1 = __builtin_bit_cast(bf16x8, ldsB[(ch * 32 + kk * 2 + 1) * 64 + l]);
                    acc0 = __builtin_amdgcn_mfma_f32_32x32x16_bf16(A[ch * 16 + kk], b0, acc0, 0, 0, 0);
                    acc1 = __builtin_amdgcn_mfma_f32_32x32x16_bf16(A[ch * 16 + kk], b1, acc1, 0, 0, 0);
                }
            }
        }

        // ---- activations + state update (all 4 gates live in this lane) ----
        float htv[8];
#pragma unroll
        for (int nt = 0; nt < 2; ++nt) {
            f32x16 ac = nt ? acc1 : acc0;
#pragma unroll
            for (int d = 0; d < 4; ++d) {
                float g  = fast_tanh(ac[d]);
                float ii = fast_sigmoid(ac[4 + d]);
                float ff = fast_sigmoid(ac[8 + d]);
                float oo = fast_sigmoid(ac[12 + d]);
                float cc = fmaf(ct[nt * 4 + d], ff, g * ii);
                ct[nt * 4 + d] = cc;
                htv[nt * 4 + d] = fast_tanh(cc) * oo;
            }
        }

        // ---- store ht(t) as bf16, B-fragment order ----
        // fast: plain store (acks at this XCD's L2, stays in L2). slow: sc1 device-scope.
        {
            unsigned short* gW = htW + (c << 16);
            int kkw  = (r << 1) + (w >> 1);
            int slot = ((w & 1) << 5) + l31;
#pragma unroll
            for (int nt = 0; nt < 2; ++nt) {
                unsigned lo = pk2bf(htv[nt * 4 + 0], htv[nt * 4 + 1]);
                unsigned hi = pk2bf(htv[nt * 4 + 2], htv[nt * 4 + 3]);
                unsigned long long v = (unsigned long long)lo | ((unsigned long long)hi << 32);
                unsigned long long* dst =
                    (unsigned long long*)(gW + (((kkw * 2 + nt) * 64 + slot) * 8 + (h5 << 2)));
                if (fast) *dst = v;
                else __hip_atomic_store(dst, v, __ATOMIC_RELAXED, __HIP_MEMORY_SCOPE_AGENT);
            }
        }

        // ---- group barrier: per-wg flag (sc1) + wave0 parallel poll ----
        asm volatile("s_waitcnt vmcnt(0)" ::: "memory");   // ht stores ack'd (L2 or HBM)
        __syncthreads();                                    // all 4 waves' stores ack'd
        unsigned target = (unsigned)(t + 1);
        if (tid == 0)
            __hip_atomic_store(&gflags[r], target, __ATOMIC_RELAXED, __HIP_MEMORY_SCOPE_AGENT);
        if (w == 0) {
            const unsigned* fp = gflags + l31;             // lanes l and l+32 read same flag
            while (true) {
                unsigned v = __hip_atomic_load(fp, __ATOMIC_RELAXED, __HIP_MEMORY_SCOPE_AGENT);
                if (__ballot(v >= target) == ~0ull) break;
                __builtin_amdgcn_s_sleep(1);
            }
        }
        __syncthreads();

        xv0 = nx0; xv1 = nx1;
        const unsigned short* tmp = htR; htR = htW; htW = (unsigned short*)tmp;
    }

    // ---- final projection: out[b][cls] = Wph[cls,:] . ht[:,b] + bp[cls] ----
    //   elem(h, b) at region c*65536 + (h>>4)*1024 + ((b>>5)&1)*512 + ((h>>3)&1)*256 + (b&31)*8 + (h&7)
    // Lane l covers h in [16l, 16l+16): two 16B loads at +0 and +256 elems.
    {
        const unsigned short* hfin = htR + (c << 16);
        for (int p = w; p < 20; p += 4) {
            int bloc = (r << 1) + (p / 10);            // in-group batch 0..63
            int bb   = (c << 6) + bloc;
            int cls  = p % 10;
            const unsigned short* base = hfin + l * 1024 + ((bloc >> 5) & 1) * 512
                                              + (bloc & 31) * 8;
            u32x4 u0, u1;
            if (fast) { u0 = load16_sc0(base); u1 = load16_sc0(base + 256); }
            else      { u0 = load16_sc1(base); u1 = load16_sc1(base + 256); }
            const float* wp = Wph + (unsigned)cls * HID + (unsigned)l * 16;
            float s = 0.f;
#pragma unroll
            for (int e = 0; e < 4; ++e) {
                s = fmaf(wp[2 * e],         bflo(u0[e]), s);
                s = fmaf(wp[2 * e + 1],     bfhi(u0[e]), s);
                s = fmaf(wp[8 + 2 * e],     bflo(u1[e]), s);
                s = fmaf(wp[8 + 2 * e + 1], bfhi(u1[e]), s);
            }
#pragma unroll
            for (int off = 32; off > 0; off >>= 1) s += __shfl_xor(s, off, 64);
            if (l == 0) out[bb * 10 + cls] = s + bp[cls];
        }
    }
}

extern "C" void kernel_launch(void* const* d_in, const int* in_sizes, int n_in,
                              void* d_out, int out_size, void* d_ws, size_t ws_size,
                              hipStream_t stream) {
    const float* x   = (const float*)d_in[0];
    const float* Wgx = (const float*)d_in[1];
    const float* Wgh = (const float*)d_in[2];
    const float* bg  = (const float*)d_in[3];
    const float* Wix = (const float*)d_in[4];
    const float* Wih = (const float*)d_in[5];
    const float* bi  = (const float*)d_in[6];
    const float* Wfx = (const float*)d_in[7];
    const float* Wfh = (const float*)d_in[8];
    const float* bf_ = (const float*)d_in[9];
    const float* Wox = (const float*)d_in[10];
    const float* Woh = (const float*)d_in[11];
    const float* bo  = (const float*)d_in[12];
    const float* Wph = (const float*)d_in[13];
    const float* bp  = (const float*)d_in[14];
    float* out = (float*)d_out;

    char* ws = (char*)d_ws;
    unsigned short* htA = (unsigned short*)ws;                 // 1 MiB, ht buffer A (frag order)
    unsigned short* htB = (unsigned short*)(ws + (1 << 20));   // 1 MiB, ht buffer B
    unsigned*      sync = (unsigned*)(ws + (2 << 20));         // 3 KiB: flags + xcd slots

    lstm_init<<<dim3(20), dim3(256), 0, stream>>>(sync, out);

    static int lds_set = 0;
    if (!lds_set) {   // idempotent host-side config; allows 128 KiB dynamic LDS
        hipFuncSetAttribute((const void*)lstm_main,
                            hipFuncAttributeMaxDynamicSharedMemorySize, 131072);
        lds_set = 1;
    }
    lstm_main<<<dim3(256), dim3(256), 131072, stream>>>(
        x, Wgx, Wgh, bg, Wix, Wih, bi, Wfx, Wfh, bf_,
        Wox, Woh, bo, Wph, bp, out, htA, htB, sync);
}